// Round 2
// baseline (273.979 us; speedup 1.0000x reference)
//
#include <hip/hip_runtime.h>

// SeriesDecompEMA: res = x - ma, ma = EMA(x, alpha) per (b, c) sequence over T.
// B=64, T=720, C=512, f32. ma[t] = beta*ma[t-1] + alpha*x[t], ma[0]=x[0], beta=1-alpha.
// Chunked parallel scan, J=16 chunks of L=45, float4-vectorized over c (contiguous dim).
//
// Kernel A: per-(b,j,c4) thread computes chunk-local partial EMA end value (seed 0).
// Kernel B: carry-in E_j = sum_{k<j} s_k * (beta^L)^(j-1-k) (Horner), re-scan chunk
//           seeded with E_j, write res and ma. x re-read in B should hit L3 (94 MB < 256 MB).

constexpr int kB  = 64;
constexpr int kT  = 720;
constexpr int kC  = 512;
constexpr int kC4 = kC / 4;     // float4 groups per row
constexpr int kJ  = 16;         // chunks per sequence
constexpr int kL  = 45;         // chunk length; kJ*kL == kT
constexpr int kNT = kB * kJ * kC4;   // 131072 threads

__global__ __launch_bounds__(256, 2) void ema_partials(const float4* __restrict__ x,
                                                       const float* __restrict__ alphap,
                                                       float4* __restrict__ s) {
    const int tid = blockIdx.x * 256 + threadIdx.x;   // = (b*kJ + j)*kC4 + c4
    const int c   = tid & (kC4 - 1);
    const int bj  = tid >> 7;
    const int j   = bj & (kJ - 1);
    const int b   = bj >> 4;
    const float alpha = alphap[0];
    const float beta  = 1.0f - alpha;

    const float4* xp = x + (size_t)(b * kT + j * kL) * kC4 + c;

    // first element of the whole sequence has weight 1 (ma[0]=x[0]); all others alpha
    const float4 v0 = xp[0];
    const float w0  = (j == 0) ? 1.0f : alpha;
    float p0 = w0 * v0.x, p1 = w0 * v0.y, p2 = w0 * v0.z, p3 = w0 * v0.w;
    #pragma unroll
    for (int i = 1; i < kL; ++i) {
        const float4 u = xp[i * kC4];
        p0 = fmaf(beta, p0, alpha * u.x);
        p1 = fmaf(beta, p1, alpha * u.y);
        p2 = fmaf(beta, p2, alpha * u.z);
        p3 = fmaf(beta, p3, alpha * u.w);
    }
    s[tid] = make_float4(p0, p1, p2, p3);   // coalesced
}

__global__ __launch_bounds__(256, 2) void ema_apply(const float4* __restrict__ x,
                                                    const float* __restrict__ alphap,
                                                    const float4* __restrict__ s,
                                                    float4* __restrict__ res,
                                                    float4* __restrict__ ma) {
    const int tid = blockIdx.x * 256 + threadIdx.x;
    const int c   = tid & (kC4 - 1);
    const int bj  = tid >> 7;
    const int j   = bj & (kJ - 1);
    const int b   = bj >> 4;
    const float alpha = alphap[0];
    const float beta  = 1.0f - alpha;

    // betaL = beta^kL via unrolled multiplies (avoids ocml powf call)
    float betaL = 1.0f;
    #pragma unroll
    for (int i = 0; i < kL; ++i) betaL *= beta;

    // E_j = sum_{k<j} s_k * betaL^(j-1-k), Horner ascending k. j is wave-uniform.
    const float4* sp = s + (size_t)(b * kJ) * kC4 + c;
    float E0 = 0.0f, E1 = 0.0f, E2 = 0.0f, E3 = 0.0f;
    for (int k = 0; k < j; ++k) {
        const float4 sv = sp[k * kC4];
        E0 = fmaf(E0, betaL, sv.x);
        E1 = fmaf(E1, betaL, sv.y);
        E2 = fmaf(E2, betaL, sv.z);
        E3 = fmaf(E3, betaL, sv.w);
    }

    const size_t base = (size_t)(b * kT + j * kL) * kC4 + c;
    const float4* xp = x   + base;
    float4*       rp = res + base;
    float4*       mp = ma  + base;

    // peel i=0: weight is 1 only at the global t=0 (j==0), where E==0 so e = x[0] exactly
    {
        const float4 u = xp[0];
        const float w = (j == 0) ? 1.0f : alpha;
        E0 = fmaf(beta, E0, w * u.x);
        E1 = fmaf(beta, E1, w * u.y);
        E2 = fmaf(beta, E2, w * u.z);
        E3 = fmaf(beta, E3, w * u.w);
        mp[0] = make_float4(E0, E1, E2, E3);
        rp[0] = make_float4(u.x - E0, u.y - E1, u.z - E2, u.w - E3);
    }
    #pragma unroll
    for (int i = 1; i < kL; ++i) {
        const float4 u = xp[i * kC4];
        E0 = fmaf(beta, E0, alpha * u.x);
        E1 = fmaf(beta, E1, alpha * u.y);
        E2 = fmaf(beta, E2, alpha * u.z);
        E3 = fmaf(beta, E3, alpha * u.w);
        mp[i * kC4] = make_float4(E0, E1, E2, E3);
        rp[i * kC4] = make_float4(u.x - E0, u.y - E1, u.z - E2, u.w - E3);
    }
}

extern "C" void kernel_launch(void* const* d_in, const int* in_sizes, int n_in,
                              void* d_out, int out_size, void* d_ws, size_t ws_size,
                              hipStream_t stream) {
    const float4* x     = (const float4*)d_in[0];
    const float* alphap = (const float*)d_in[1];
    float4* res = (float4*)d_out;                        // outputs concatenated: res then ma
    float4* ma  = res + (size_t)kB * kT * kC4;
    float4* s   = (float4*)d_ws;                         // kB*kJ*kC floats = 2 MB

    const int nblk = kNT / 256;                          // 512
    ema_partials<<<nblk, 256, 0, stream>>>(x, alphap, s);
    ema_apply   <<<nblk, 256, 0, stream>>>(x, alphap, s, res, ma);
}